// Round 11
// baseline (71.787 us; speedup 1.0000x reference)
//
#include <hip/hip_runtime.h>

#define T_TOK   32768
#define HDIM    2048
#define NEXP    8
#define SEQ     8192
#define NBATCH  4
#define ALPHA   0.1f

#define BLOCK   512
#define TPB     64                 // tokens per block: 8 waves x 8
#define NBLK    (T_TOK / TPB)      // 512
#define BPB     (SEQ / TPB)        // 128 blocks per batch
#define H4      (HDIM / 4)         // 512 float4 per row
#define NJ      (H4 / 16)          // 32 j-phases (16-lane H split)

// ---------------------------------------------------------------- main gate
// EXACT r4 inner loop (empirical argmax: 63.4 us total): M=2, 16-lane groups,
// w staged in LDS, 2-phase x lookahead, w-prefetch interleaved BETWEEN the
// two COMPUTE_HALFs and x-refill last (this interleave beat x-first by ~2-4us
// in r9's A/B). __launch_bounds__(512,4) as in r4. Structure upgrades kept
// from r7+: no init kernel, per-block private ws slots, tiny finalize.
// All register-array indices compile-time static (rule #20).
__global__ __launch_bounds__(BLOCK, 4) void gate_kernel(
    const float* __restrict__ x,       // [T_TOK, HDIM]
    const float* __restrict__ w,       // [NEXP, HDIM]
    float* __restrict__ out_idx,       // [T_TOK, 2] float-encoded
    float* __restrict__ out_wt,        // [T_TOK, 2]
    float* __restrict__ ws)            // [NBLK*16] per-block partials
{
    __shared__ float4 wlds[NEXP * H4]; // 64 KB
    __shared__ float sacc[16];

    const int tid  = threadIdx.x;
    const int wid  = tid >> 6;
    const int lane = tid & 63;
    const int grp  = lane >> 4;        // 4 groups per wave
    const int col  = lane & 15;        // 16-lane H split

    // stage weights: 4096 float4s, 8 per thread, coalesced
    const float4* w4 = (const float4*)w;
    #pragma unroll
    for (int i = 0; i < 8; ++i)
        wlds[tid + i * BLOCK] = w4[tid + i * BLOCK];
    if (tid < 16) sacc[tid] = 0.0f;
    __syncthreads();

    const int tok0 = blockIdx.x * TPB + wid * 8 + grp * 2;   // group's 1st token

    const float4* xp0 = (const float4*)x + (size_t)tok0 * H4 + col;
    const float4* xp1 = xp0 + H4;                            // 2nd token

    float acc[2][NEXP];
    #pragma unroll
    for (int t = 0; t < 2; ++t)
        #pragma unroll
        for (int e = 0; e < NEXP; ++e) acc[t][e] = 0.0f;

    float4 xb0[2], xb1[2];             // x slots for even/odd phases (2 tokens)
    float4 wA[4], wB[4];               // expert halves for current phase (LDS)

    // prologue
    xb0[0] = xp0[0];        xb0[1] = xp1[0];
    xb1[0] = xp0[16];       xb1[1] = xp1[16];
    #pragma unroll
    for (int e = 0; e < 4; ++e) wA[e] = wlds[e * H4 + col];
    #pragma unroll
    for (int e = 0; e < 4; ++e) wB[e] = wlds[(e + 4) * H4 + col];

#define FMA4(ACC, XV, WV)                      \
    ACC = fmaf((XV).x, (WV).x, ACC);           \
    ACC = fmaf((XV).y, (WV).y, ACC);           \
    ACC = fmaf((XV).z, (WV).z, ACC);           \
    ACC = fmaf((XV).w, (WV).w, ACC);

#define COMPUTE_HALF(XB, WH, EBASE)            \
    _Pragma("unroll")                          \
    for (int e = 0; e < 4; ++e) {              \
        const float4 wv = WH[e];               \
        FMA4(acc[0][(EBASE) + e], XB[0], wv);  \
        FMA4(acc[1][(EBASE) + e], XB[1], wv);  \
    }

    #pragma unroll 1
    for (int jj = 0; jj < NJ - 2; jj += 2) {
        // ---- phase jj (even slot) — r4 interleave verbatim
        COMPUTE_HALF(xb0, wA, 0)
        #pragma unroll
        for (int e = 0; e < 4; ++e) wA[e] = wlds[e * H4 + (jj + 1) * 16 + col];
        COMPUTE_HALF(xb0, wB, 4)
        #pragma unroll
        for (int e = 0; e < 4; ++e) wB[e] = wlds[(e + 4) * H4 + (jj + 1) * 16 + col];
        xb0[0] = xp0[(jj + 2) * 16];
        xb0[1] = xp1[(jj + 2) * 16];

        // ---- phase jj+1 (odd slot)
        COMPUTE_HALF(xb1, wA, 0)
        #pragma unroll
        for (int e = 0; e < 4; ++e) wA[e] = wlds[e * H4 + (jj + 2) * 16 + col];
        COMPUTE_HALF(xb1, wB, 4)
        #pragma unroll
        for (int e = 0; e < 4; ++e) wB[e] = wlds[(e + 4) * H4 + (jj + 2) * 16 + col];
        xb1[0] = xp0[(jj + 3) * 16];
        xb1[1] = xp1[(jj + 3) * 16];
    }

    // ---- peeled tail: phases NJ-2, NJ-1
    {
        COMPUTE_HALF(xb0, wA, 0)
        #pragma unroll
        for (int e = 0; e < 4; ++e) wA[e] = wlds[e * H4 + (NJ - 1) * 16 + col];
        COMPUTE_HALF(xb0, wB, 4)
        #pragma unroll
        for (int e = 0; e < 4; ++e) wB[e] = wlds[(e + 4) * H4 + (NJ - 1) * 16 + col];
        COMPUTE_HALF(xb1, wA, 0)
        COMPUTE_HALF(xb1, wB, 4)
    }

    // reduce partials across the 16-lane group (4 groups in parallel)
    #pragma unroll
    for (int t = 0; t < 2; ++t)
        #pragma unroll
        for (int e = 0; e < NEXP; ++e) {
            float v = acc[t][e];
            v += __shfl_xor(v, 1);
            v += __shfl_xor(v, 2);
            v += __shfl_xor(v, 4);
            v += __shfl_xor(v, 8);
            acc[t][e] = v;             // all 16 lanes hold both tokens' logits
        }

    // lane-local epilogue: lane col handles token (col & 1) via static select
    const bool selLo = (col & 1) != 0;
    float l[NEXP];
    #pragma unroll
    for (int e = 0; e < NEXP; ++e)
        l[e] = selLo ? acc[1][e] : acc[0][e];

    float mx = l[0];
    #pragma unroll
    for (int e = 1; e < NEXP; ++e) mx = fmaxf(mx, l[e]);

    float p[NEXP];
    float psum = 0.0f;
    #pragma unroll
    for (int e = 0; e < NEXP; ++e) { p[e] = __expf(l[e] - mx); psum += p[e]; }
    const float inv = 1.0f / psum;
    float s[NEXP];
    #pragma unroll
    for (int e = 0; e < NEXP; ++e) s[e] = p[e] * inv;

    float s1 = s[0]; int i1 = 0;       // strict > keeps lowest index (lax.top_k)
    #pragma unroll
    for (int e = 1; e < NEXP; ++e) if (s[e] > s1) { s1 = s[e]; i1 = e; }
    float s2 = -1.0f; int i2 = 0;
    #pragma unroll
    for (int e = 0; e < NEXP; ++e) if (e != i1 && s[e] > s2) { s2 = s[e]; i2 = e; }

    const float wsum = s1 + s2 + 1e-20f;
    const float w1 = s1 / wsum;
    const float w2 = s2 / wsum;

    if (col < 2) {
        const int tok = tok0 + (col & 1);
        ((float2*)out_idx)[tok] = make_float2((float)i1, (float)i2);
        ((float2*)out_wt)[tok]  = make_float2(w1, w2);
    }

    // aux partials: lanes col 0,1 of each group carry their token's stats
    const float sel = (col < 2) ? 1.0f : 0.0f;
    #pragma unroll
    for (int e = 0; e < NEXP; ++e) {
        float pi = s[e] * sel;
        float ce = (((i1 == e) ? 1.0f : 0.0f) + ((i2 == e) ? 1.0f : 0.0f)) * sel;
        pi += __shfl_xor(pi, 1);  ce += __shfl_xor(ce, 1);   // token pair
        pi += __shfl_xor(pi, 16); ce += __shfl_xor(ce, 16);  // groups
        pi += __shfl_xor(pi, 32); ce += __shfl_xor(ce, 32);
        if (lane == 0) {
            atomicAdd(&sacc[e], pi);
            atomicAdd(&sacc[8 + e], ce);
        }
    }
    __syncthreads();
    // private per-block slot: fully overwritten every launch (no init needed)
    if (tid < 16)
        ws[blockIdx.x * 16 + tid] = sacc[tid];
}

// ---------------------------------------------------------------- finalize
// Reduce 512 blocks x 16 partials (32 KB, L2-resident) and emit aux loss.
__global__ __launch_bounds__(256) void finalize_kernel(const float* __restrict__ ws,
                                                       float* __restrict__ out_aux) {
    __shared__ float sfin[NBATCH][16];
    const int t    = threadIdx.x;
    const int b    = t >> 6;          // one wave per batch
    const int lane = t & 63;
    const int slot = lane & 15;

    float v = 0.0f;
    for (int j = lane >> 4; j < BPB; j += 4)          // 32 blocks per lane
        v += ws[(b * BPB + j) * 16 + slot];
    v += __shfl_xor(v, 16);
    v += __shfl_xor(v, 32);
    if (lane < 16) sfin[b][slot] = v;
    __syncthreads();

    if (t == 0) {
        float aux = 0.0f;
        #pragma unroll
        for (int bb = 0; bb < NBATCH; ++bb) {
            float dot = 0.0f;
            #pragma unroll
            for (int e = 0; e < NEXP; ++e) {
                const float pi = sfin[bb][e] / (float)SEQ;
                const float ce = sfin[bb][8 + e] * ((float)NEXP / (float)(SEQ * 2));
                dot = fmaf(ce, pi, dot);
            }
            aux += dot;
        }
        out_aux[0] = aux * (1.0f / NBATCH) * ALPHA;
    }
}

// ---------------------------------------------------------------- launch
extern "C" void kernel_launch(void* const* d_in, const int* in_sizes, int n_in,
                              void* d_out, int out_size, void* d_ws, size_t ws_size,
                              hipStream_t stream) {
    const float* x = (const float*)d_in[0];   // hidden_states [4,8192,2048]
    const float* w = (const float*)d_in[1];   // weight [8,2048]

    float* out     = (float*)d_out;
    float* out_idx = out;                  // [32768,2]
    float* out_wt  = out + 2 * T_TOK;      // [32768,2]
    float* out_aux = out + 4 * T_TOK;      // [1]
    float* ws      = (float*)d_ws;         // [NBLK*16]

    gate_kernel<<<NBLK, BLOCK, 0, stream>>>(x, w, out_idx, out_wt, ws);
    finalize_kernel<<<1, 256, 0, stream>>>(ws, out_aux);
}

// Round 12
// 63.600 us; speedup vs baseline: 1.1287x; 1.1287x over previous
//
#include <hip/hip_runtime.h>

#define T_TOK   32768
#define HDIM    2048
#define NEXP    8
#define SEQ     8192
#define NBATCH  4
#define ALPHA   0.1f

#define BLOCK   512
#define TPB     64                 // tokens per block: 8 waves x 8
#define NBLK    (T_TOK / TPB)      // 512
#define H4      (HDIM / 4)         // 512 float4 per row
#define NJ      (H4 / 16)          // 32 j-phases (16-lane H split)

// ---------------------------------------------------------------- init ws
__global__ __launch_bounds__(64) void init_ws_kernel(float* ws) {
    ws[threadIdx.x] = 0.0f;        // [0..31] pi_sum, [32..63] ce_cnt
}

// ---------------------------------------------------------------- main gate
// Byte-exact restoration of the round-4 kernel (best measured: 63.4 us).
// Weights staged in LDS (64 KB) once per block; j-loop reads w via
// ds_read_b128 (broadcast across the 4 token-groups = free), x streamed from
// HBM with 2-phase register lookahead. 512 thr/block, 2 blocks/CU ->
// 4 waves/SIMD. Rounds 9-11 established that issue-order / pipeline-depth /
// kernel-count variants of this body all land in the same 63-72 us noise
// band; this is the empirical argmax configuration.
__global__ __launch_bounds__(BLOCK, 4) void gate_kernel(
    const float* __restrict__ x,       // [T_TOK, HDIM]
    const float* __restrict__ w,       // [NEXP, HDIM]
    float* __restrict__ out_idx,       // [T_TOK, 2] float-encoded
    float* __restrict__ out_wt,        // [T_TOK, 2]
    float* __restrict__ ws)            // [64]
{
    __shared__ float4 wlds[NEXP * H4]; // 64 KB
    __shared__ float sacc[16];

    const int tid  = threadIdx.x;
    const int wid  = tid >> 6;
    const int lane = tid & 63;
    const int grp  = lane >> 4;
    const int col  = lane & 15;

    // stage weights: 4096 float4s, 8 per thread, coalesced
    const float4* w4 = (const float4*)w;
    #pragma unroll
    for (int i = 0; i < 8; ++i)
        wlds[tid + i * BLOCK] = w4[tid + i * BLOCK];
    if (tid < 16) sacc[tid] = 0.0f;
    __syncthreads();

    const int tok0 = blockIdx.x * TPB + wid * 8 + grp * 2;   // group's 1st token
    const int b    = (blockIdx.x * TPB) / SEQ;               // uniform per block

    const float4* xp0 = (const float4*)x + (size_t)tok0 * H4 + col;
    const float4* xp1 = xp0 + H4;                            // 2nd token

    float acc[2][NEXP];
    #pragma unroll
    for (int t = 0; t < 2; ++t)
        #pragma unroll
        for (int e = 0; e < NEXP; ++e) acc[t][e] = 0.0f;

    float4 xb0[2], xb1[2];             // x slots for even/odd phases (2 tokens)
    float4 wA[4], wB[4];               // expert halves for current phase (LDS)

    // prologue
    xb0[0] = xp0[0];        xb0[1] = xp1[0];
    xb1[0] = xp0[16];       xb1[1] = xp1[16];
    #pragma unroll
    for (int e = 0; e < 4; ++e) wA[e] = wlds[e * H4 + col];
    #pragma unroll
    for (int e = 0; e < 4; ++e) wB[e] = wlds[(e + 4) * H4 + col];

#define FMA4(ACC, XV, WV)                      \
    ACC = fmaf((XV).x, (WV).x, ACC);           \
    ACC = fmaf((XV).y, (WV).y, ACC);           \
    ACC = fmaf((XV).z, (WV).z, ACC);           \
    ACC = fmaf((XV).w, (WV).w, ACC);

#define COMPUTE_HALF(XB, WH, EBASE)            \
    _Pragma("unroll")                          \
    for (int e = 0; e < 4; ++e) {              \
        const float4 wv = WH[e];               \
        FMA4(acc[0][(EBASE) + e], XB[0], wv);  \
        FMA4(acc[1][(EBASE) + e], XB[1], wv);  \
    }

    #pragma unroll 1
    for (int jj = 0; jj < NJ - 2; jj += 2) {
        // ---- phase jj (even slot)
        COMPUTE_HALF(xb0, wA, 0)
        #pragma unroll
        for (int e = 0; e < 4; ++e) wA[e] = wlds[e * H4 + (jj + 1) * 16 + col];
        COMPUTE_HALF(xb0, wB, 4)
        #pragma unroll
        for (int e = 0; e < 4; ++e) wB[e] = wlds[(e + 4) * H4 + (jj + 1) * 16 + col];
        xb0[0] = xp0[(jj + 2) * 16];
        xb0[1] = xp1[(jj + 2) * 16];

        // ---- phase jj+1 (odd slot)
        COMPUTE_HALF(xb1, wA, 0)
        #pragma unroll
        for (int e = 0; e < 4; ++e) wA[e] = wlds[e * H4 + (jj + 2) * 16 + col];
        COMPUTE_HALF(xb1, wB, 4)
        #pragma unroll
        for (int e = 0; e < 4; ++e) wB[e] = wlds[(e + 4) * H4 + (jj + 2) * 16 + col];
        xb1[0] = xp0[(jj + 3) * 16];
        xb1[1] = xp1[(jj + 3) * 16];
    }

    // ---- peeled tail: phases NJ-2, NJ-1
    {
        COMPUTE_HALF(xb0, wA, 0)
        #pragma unroll
        for (int e = 0; e < 4; ++e) wA[e] = wlds[e * H4 + (NJ - 1) * 16 + col];
        COMPUTE_HALF(xb0, wB, 4)
        #pragma unroll
        for (int e = 0; e < 4; ++e) wB[e] = wlds[(e + 4) * H4 + (NJ - 1) * 16 + col];
        COMPUTE_HALF(xb1, wA, 0)
        COMPUTE_HALF(xb1, wB, 4)
    }

    // reduce partials across the 16-lane group (4 groups in parallel)
    #pragma unroll
    for (int t = 0; t < 2; ++t)
        #pragma unroll
        for (int e = 0; e < NEXP; ++e) {
            float v = acc[t][e];
            v += __shfl_xor(v, 1);
            v += __shfl_xor(v, 2);
            v += __shfl_xor(v, 4);
            v += __shfl_xor(v, 8);
            acc[t][e] = v;             // all 16 lanes hold both tokens' logits
        }

    // lane-local epilogue: lane col handles token (col & 1); only col<2 commits
    const int t = col & 1;
    float l[NEXP];
    #pragma unroll
    for (int e = 0; e < NEXP; ++e) l[e] = acc[t][e];

    float mx = l[0];
    #pragma unroll
    for (int e = 1; e < NEXP; ++e) mx = fmaxf(mx, l[e]);

    float p[NEXP];
    float psum = 0.0f;
    #pragma unroll
    for (int e = 0; e < NEXP; ++e) { p[e] = __expf(l[e] - mx); psum += p[e]; }
    const float inv = 1.0f / psum;
    float s[NEXP];
    #pragma unroll
    for (int e = 0; e < NEXP; ++e) s[e] = p[e] * inv;

    float s1 = s[0]; int i1 = 0;       // strict > keeps lowest index (lax.top_k)
    #pragma unroll
    for (int e = 1; e < NEXP; ++e) if (s[e] > s1) { s1 = s[e]; i1 = e; }
    float s2 = -1.0f; int i2 = 0;
    #pragma unroll
    for (int e = 0; e < NEXP; ++e) if (e != i1 && s[e] > s2) { s2 = s[e]; i2 = e; }

    const float wsum = s1 + s2 + 1e-20f;
    const float w1 = s1 / wsum;
    const float w2 = s2 / wsum;

    if (col < 2) {
        const int tok = tok0 + t;
        ((float2*)out_idx)[tok] = make_float2((float)i1, (float)i2);
        ((float2*)out_wt)[tok]  = make_float2(w1, w2);
    }

    // aux partials: lanes col 0,1 of each group carry their token's stats
    const float sel = (col < 2) ? 1.0f : 0.0f;
    #pragma unroll
    for (int e = 0; e < NEXP; ++e) {
        float pi = s[e] * sel;
        float ce = (((i1 == e) ? 1.0f : 0.0f) + ((i2 == e) ? 1.0f : 0.0f)) * sel;
        pi += __shfl_xor(pi, 1);  ce += __shfl_xor(ce, 1);   // token pair
        pi += __shfl_xor(pi, 16); ce += __shfl_xor(ce, 16);  // groups
        pi += __shfl_xor(pi, 32); ce += __shfl_xor(ce, 32);
        if (lane == 0) {
            atomicAdd(&sacc[e], pi);
            atomicAdd(&sacc[8 + e], ce);
        }
    }
    __syncthreads();
    if (tid < 8)
        atomicAdd(&ws[b * NEXP + tid], sacc[tid]);
    else if (tid < 16)
        atomicAdd(&ws[32 + b * NEXP + (tid - 8)], sacc[tid]);
}

// ---------------------------------------------------------------- finalize
__global__ __launch_bounds__(64) void finalize_kernel(const float* __restrict__ ws,
                                                      float* __restrict__ out_aux) {
    if (threadIdx.x == 0) {
        float aux = 0.0f;
        #pragma unroll
        for (int b = 0; b < NBATCH; ++b) {
            float dot = 0.0f;
            #pragma unroll
            for (int e = 0; e < NEXP; ++e) {
                const float ce = ws[32 + b * NEXP + e] * ((float)NEXP / (float)(SEQ * 2));
                const float pi = ws[b * NEXP + e] / (float)SEQ;
                dot = fmaf(ce, pi, dot);
            }
            aux += dot;
        }
        out_aux[0] = aux * (1.0f / NBATCH) * ALPHA;
    }
}

// ---------------------------------------------------------------- launch
extern "C" void kernel_launch(void* const* d_in, const int* in_sizes, int n_in,
                              void* d_out, int out_size, void* d_ws, size_t ws_size,
                              hipStream_t stream) {
    const float* x = (const float*)d_in[0];   // hidden_states [4,8192,2048]
    const float* w = (const float*)d_in[1];   // weight [8,2048]

    float* out     = (float*)d_out;
    float* out_idx = out;                  // [32768,2]
    float* out_wt  = out + 2 * T_TOK;      // [32768,2]
    float* out_aux = out + 4 * T_TOK;      // [1]
    float* ws      = (float*)d_ws;

    init_ws_kernel<<<1, 64, 0, stream>>>(ws);
    gate_kernel<<<NBLK, BLOCK, 0, stream>>>(x, w, out_idx, out_wt, ws);
    finalize_kernel<<<1, 64, 0, stream>>>(ws, out_aux);
}